// Round 1
// baseline (549.446 us; speedup 1.0000x reference)
//
#include <hip/hip_runtime.h>
#include <hip/hip_bf16.h>

#define NSEQ 512
#define DDIM 128
#define NPOS (NSEQ*NSEQ)

typedef __bf16 bf16x8 __attribute__((ext_vector_type(8)));
typedef float f32x4 __attribute__((ext_vector_type(4)));
typedef unsigned short us4 __attribute__((ext_vector_type(4)));
typedef unsigned int u32x4 __attribute__((ext_vector_type(4)));

__device__ __forceinline__ unsigned short f2bf(float f){
  unsigned int u = __float_as_uint(f);
  u += 0x7fffu + ((u >> 16) & 1u);
  return (unsigned short)(u >> 16);
}
__device__ __forceinline__ float bf2f(unsigned short s){
  return __uint_as_float(((unsigned int)s) << 16);
}
__device__ __forceinline__ float sigmoidf_(float x){
  return 1.0f/(1.0f + __expf(-x));
}

// ---------------- K0: weight prep (transpose to [out_col][k], bf16) ----------
// wt rows: [0..255]=W_lr^T, [256..511]=W_gate^T, [512..639]=W_og^T, [640..767]=W_op^T
__global__ void k_prep(const float* __restrict__ Wlr, const float* __restrict__ Wgate,
                       const float* __restrict__ Wog, const float* __restrict__ Wop,
                       unsigned short* __restrict__ wt)
{
  int idx = blockIdx.x*256 + threadIdx.x;
  if (idx >= 768*128) return;
  int row = idx >> 7, k = idx & 127;
  float v;
  if (row < 256)      v = Wlr[k*256 + row];
  else if (row < 512) v = Wgate[k*256 + (row-256)];
  else if (row < 640) v = Wog[k*128 + (row-512)];
  else                v = Wop[k*128 + (row-640)];
  wt[idx] = f2bf(v);
}

// K=128 MFMA tile: A rows = out rows, B rows = out cols, both k-contiguous in LDS.
// 16B-padded rows ([128][136]) -> bank-start 4*((r+q)&7): uniform 8 lanes/quad = optimal.
__device__ __forceinline__ void mfma_k128(const unsigned short (&A)[128][136],
                                          const unsigned short (&B)[128][136],
                                          int wrow, int wcol, int lr_, int lq,
                                          f32x4 (&acc)[4][4])
{
  #pragma unroll
  for (int s = 0; s < 4; ++s){
    const int k0 = s*32 + lq*8;
    bf16x8 a[4], b[4];
    #pragma unroll
    for (int f = 0; f < 4; ++f)
      a[f] = *reinterpret_cast<const bf16x8*>(&A[wrow*64 + f*16 + lr_][k0]);
    #pragma unroll
    for (int f = 0; f < 4; ++f)
      b[f] = *reinterpret_cast<const bf16x8*>(&B[wcol*64 + f*16 + lr_][k0]);
    #pragma unroll
    for (int fi = 0; fi < 4; ++fi)
      #pragma unroll
      for (int fj = 0; fj < 4; ++fj)
        acc[fi][fj] = __builtin_amdgcn_mfma_f32_16x16x32_bf16(a[fi], b[fj], acc[fi][fj], 0, 0, 0);
  }
}

// ---------------- K1: LN1 + (lr,gate,og) GEMMs + gating ---------------------
// Block: 128 positions x (5 chunks of 128 out-cols). 256 threads, 4 waves (2x2).
__global__ __launch_bounds__(256, 2)
void k1(const float* __restrict__ Zraw, const float* __restrict__ mask,
        const float* __restrict__ ln1g, const float* __restrict__ ln1b,
        const float* __restrict__ blr, const float* __restrict__ bgate,
        const float* __restrict__ bog,
        const unsigned short* __restrict__ wt,
        unsigned short* __restrict__ left_t, unsigned short* __restrict__ right_t,
        unsigned short* __restrict__ g_ws)
{
  __shared__ unsigned short zln[128][136];
  __shared__ unsigned short wchunk[128][136];

  const int t = threadIdx.x;
  const int posb = blockIdx.x * 128;
  const int r = t >> 1, h = t & 1;

  // ---- LN1: 2 threads per row, 64 f32 each in regs ----
  {
    const float* src = Zraw + (size_t)(posb + r)*DDIM + h*64;
    float v[64];
    float s = 0.f, sq = 0.f;
    #pragma unroll
    for (int i = 0; i < 16; ++i){
      f32x4 x = *reinterpret_cast<const f32x4*>(src + i*4);
      v[i*4+0] = x[0]; v[i*4+1] = x[1]; v[i*4+2] = x[2]; v[i*4+3] = x[3];
    }
    #pragma unroll
    for (int i = 0; i < 64; ++i){ s += v[i]; sq += v[i]*v[i]; }
    s  += __shfl_xor(s, 1);
    sq += __shfl_xor(sq, 1);
    float mu = s * (1.0f/128.0f);
    float var = sq * (1.0f/128.0f) - mu*mu;
    float rs = rsqrtf(var + 1e-5f);
    #pragma unroll
    for (int i = 0; i < 32; ++i){
      int c0 = h*64 + 2*i;
      float a = (v[2*i]   - mu)*rs*ln1g[c0]   + ln1b[c0];
      float b = (v[2*i+1] - mu)*rs*ln1g[c0+1] + ln1b[c0+1];
      *reinterpret_cast<unsigned int*>(&zln[r][c0]) =
          (unsigned int)f2bf(a) | ((unsigned int)f2bf(b) << 16);
    }
  }

  const int lane = t & 63;
  const int wid  = t >> 6;
  const int wrow = wid >> 1, wcol = wid & 1;
  const int lr_  = lane & 15, lq = lane >> 4;

  // ---- pairs: (gate_left, lr_left) -> left_t ; (gate_right, lr_right) -> right_t
  #pragma unroll 1
  for (int pair = 0; pair < 2; ++pair){
    __syncthreads();             // zln ready / previous chunk consumers done
    { // stage gate chunk
      const unsigned short* src = wt + (size_t)(256 + pair*128 + r)*128 + h*64;
      #pragma unroll
      for (int q = 0; q < 8; ++q)
        *reinterpret_cast<u32x4*>(&wchunk[r][h*64 + q*8]) =
            *reinterpret_cast<const u32x4*>(src + q*8);
    }
    __syncthreads();
    f32x4 accg[4][4];
    #pragma unroll
    for (int a1 = 0; a1 < 4; ++a1)
      #pragma unroll
      for (int a2 = 0; a2 < 4; ++a2) accg[a1][a2] = (f32x4){0.f,0.f,0.f,0.f};
    mfma_k128(zln, wchunk, wrow, wcol, lr_, lq, accg);

    float gsig[4][4][4];
    #pragma unroll
    for (int fi = 0; fi < 4; ++fi)
      #pragma unroll
      for (int fj = 0; fj < 4; ++fj){
        int col = wcol*64 + fj*16 + lr_;
        float bb = bgate[pair*128 + col];
        #pragma unroll
        for (int e = 0; e < 4; ++e)
          gsig[fi][fj][e] = sigmoidf_(accg[fi][fj][e] + bb);
      }

    __syncthreads();
    { // stage lr chunk
      const unsigned short* src = wt + (size_t)(pair*128 + r)*128 + h*64;
      #pragma unroll
      for (int q = 0; q < 8; ++q)
        *reinterpret_cast<u32x4*>(&wchunk[r][h*64 + q*8]) =
            *reinterpret_cast<const u32x4*>(src + q*8);
    }
    __syncthreads();
    f32x4 accl[4][4];
    #pragma unroll
    for (int a1 = 0; a1 < 4; ++a1)
      #pragma unroll
      for (int a2 = 0; a2 < 4; ++a2) accl[a1][a2] = (f32x4){0.f,0.f,0.f,0.f};
    mfma_k128(zln, wchunk, wrow, wcol, lr_, lq, accl);

    unsigned short* dst = pair ? right_t : left_t;
    #pragma unroll
    for (int fi = 0; fi < 4; ++fi){
      int rowb = wrow*64 + fi*16 + lq*4;
      float m0 = mask[posb + rowb + 0];
      float m1 = mask[posb + rowb + 1];
      float m2 = mask[posb + rowb + 2];
      float m3 = mask[posb + rowb + 3];
      #pragma unroll
      for (int fj = 0; fj < 4; ++fj){
        int col = wcol*64 + fj*16 + lr_;
        float bb = blr[pair*128 + col];
        us4 o;
        o[0] = f2bf((accl[fi][fj][0] + bb) * m0 * gsig[fi][fj][0]);
        o[1] = f2bf((accl[fi][fj][1] + bb) * m1 * gsig[fi][fj][1]);
        o[2] = f2bf((accl[fi][fj][2] + bb) * m2 * gsig[fi][fj][2]);
        o[3] = f2bf((accl[fi][fj][3] + bb) * m3 * gsig[fi][fj][3]);
        // [c][pos] layout: 4 consecutive positions at fixed channel col
        *reinterpret_cast<us4*>(dst + (size_t)col*NPOS + posb + rowb) = o;
      }
    }
  }

  // ---- og chunk -> g ----
  __syncthreads();
  {
    const unsigned short* src = wt + (size_t)(512 + r)*128 + h*64;
    #pragma unroll
    for (int q = 0; q < 8; ++q)
      *reinterpret_cast<u32x4*>(&wchunk[r][h*64 + q*8]) =
          *reinterpret_cast<const u32x4*>(src + q*8);
  }
  __syncthreads();
  f32x4 acco[4][4];
  #pragma unroll
  for (int a1 = 0; a1 < 4; ++a1)
    #pragma unroll
    for (int a2 = 0; a2 < 4; ++a2) acco[a1][a2] = (f32x4){0.f,0.f,0.f,0.f};
  mfma_k128(zln, wchunk, wrow, wcol, lr_, lq, acco);
  __syncthreads();   // all waves done reading zln -> reuse as g bounce buffer
  #pragma unroll
  for (int fi = 0; fi < 4; ++fi)
    #pragma unroll
    for (int fj = 0; fj < 4; ++fj){
      int col = wcol*64 + fj*16 + lr_;
      float bb = bog[col];
      #pragma unroll
      for (int e = 0; e < 4; ++e){
        int row = wrow*64 + fi*16 + lq*4 + e;
        zln[row][col] = f2bf(sigmoidf_(acco[fi][fj][e] + bb));
      }
    }
  __syncthreads();
  { // coalesced copy out: g_ws[pos][d]
    unsigned short* dstg = g_ws + (size_t)(posb + r)*DDIM + h*64;
    #pragma unroll
    for (int q = 0; q < 8; ++q)
      *reinterpret_cast<u32x4*>(dstg + q*8) =
          *reinterpret_cast<const u32x4*>(&zln[r][h*64 + q*8]);
  }
}

// ---------------- K2: per-channel NT GEMM p = L * R^T -----------------------
// A-operand = RIGHT rows (j), B-operand = LEFT rows (i)  =>  D[m=j][n=i] = p[i][j],
// so each lane stores 4 consecutive j (8B) into p[c][i][j].
__global__ __launch_bounds__(256, 3)
void k2(const unsigned short* __restrict__ left_t,
        const unsigned short* __restrict__ right_t,
        unsigned short* __restrict__ p_ws)
{
  __shared__ unsigned short At[128][72];  // right rows j, BK=64 (+8 pad)
  __shared__ unsigned short Bt[128][72];  // left  rows i

  const int t = threadIdx.x;
  const int c = blockIdx.y;
  const int it = blockIdx.x >> 2, jt = blockIdx.x & 3;
  const int i0 = it*128, j0 = jt*128;
  const int r = t >> 1, h = t & 1;
  const int lane = t & 63, wid = t >> 6;
  const int wrow = wid >> 1, wcol = wid & 1;
  const int lr_ = lane & 15, lq = lane >> 4;
  const size_t cbase = (size_t)c * NPOS;

  f32x4 acc[4][4];
  #pragma unroll
  for (int a1 = 0; a1 < 4; ++a1)
    #pragma unroll
    for (int a2 = 0; a2 < 4; ++a2) acc[a1][a2] = (f32x4){0.f,0.f,0.f,0.f};

  #pragma unroll 1
  for (int kk = 0; kk < 8; ++kk){
    const int k0 = kk*64;
    __syncthreads();
    {
      const unsigned short* sa = right_t + cbase + (size_t)(j0 + r)*NSEQ + k0 + h*32;
      const unsigned short* sb = left_t  + cbase + (size_t)(i0 + r)*NSEQ + k0 + h*32;
      #pragma unroll
      for (int q = 0; q < 4; ++q){
        *reinterpret_cast<u32x4*>(&At[r][h*32 + q*8]) = *reinterpret_cast<const u32x4*>(sa + q*8);
        *reinterpret_cast<u32x4*>(&Bt[r][h*32 + q*8]) = *reinterpret_cast<const u32x4*>(sb + q*8);
      }
    }
    __syncthreads();
    #pragma unroll
    for (int s = 0; s < 2; ++s){
      const int kl = s*32 + lq*8;
      bf16x8 a[4], b[4];
      #pragma unroll
      for (int f = 0; f < 4; ++f)
        a[f] = *reinterpret_cast<const bf16x8*>(&At[wrow*64 + f*16 + lr_][kl]);
      #pragma unroll
      for (int f = 0; f < 4; ++f)
        b[f] = *reinterpret_cast<const bf16x8*>(&Bt[wcol*64 + f*16 + lr_][kl]);
      #pragma unroll
      for (int fi = 0; fi < 4; ++fi)
        #pragma unroll
        for (int fj = 0; fj < 4; ++fj)
          acc[fi][fj] = __builtin_amdgcn_mfma_f32_16x16x32_bf16(a[fi], b[fj], acc[fi][fj], 0, 0, 0);
    }
  }

  #pragma unroll
  for (int fi = 0; fi < 4; ++fi){
    int jr = j0 + wrow*64 + fi*16 + lq*4;
    #pragma unroll
    for (int fj = 0; fj < 4; ++fj){
      int ic = i0 + wcol*64 + fj*16 + lr_;
      us4 o;
      o[0] = f2bf(acc[fi][fj][0]);
      o[1] = f2bf(acc[fi][fj][1]);
      o[2] = f2bf(acc[fi][fj][2]);
      o[3] = f2bf(acc[fi][fj][3]);
      *reinterpret_cast<us4*>(p_ws + cbase + (size_t)ic*NSEQ + jr) = o;
    }
  }
}

// ---------------- K3: LN2 + @W_op + gated residual ---------------------------
// Block: one i row, 128 consecutive j. p is [c][i][j].
__global__ __launch_bounds__(256, 2)
void k3(const unsigned short* __restrict__ p_ws, const unsigned short* __restrict__ g_ws,
        const float* __restrict__ Zraw,
        const float* __restrict__ ln2g, const float* __restrict__ ln2b,
        const unsigned short* __restrict__ wt, const float* __restrict__ obias,
        float* __restrict__ out)
{
  __shared__ unsigned short pj[128][136];   // [j][c] normalized bf16
  __shared__ unsigned short wop[128][136];  // [d][c]
  __shared__ float part[8][32][8];
  __shared__ float mu_s[128], rs_s[128];

  const int t = threadIdx.x;
  const int i = blockIdx.x >> 2;
  const int j0 = (blockIdx.x & 3) * 128;
  const int r = t >> 1, h = t & 1;

  { // stage W_op^T
    const unsigned short* src = wt + (size_t)(640 + r)*128 + h*64;
    #pragma unroll
    for (int q = 0; q < 8; ++q)
      *reinterpret_cast<u32x4*>(&wop[r][h*64 + q*8]) =
          *reinterpret_cast<const u32x4*>(src + q*8);
  }

  { // phase A: streaming stats over c (coalesced 8B loads)
    const int j4 = t & 31, grp = t >> 5;
    float s[4] = {0,0,0,0}, sq[4] = {0,0,0,0};
    const unsigned short* base = p_ws + (size_t)i*NSEQ + j0 + j4*4;
    #pragma unroll
    for (int it2 = 0; it2 < 16; ++it2){
      int c = grp + it2*8;
      us4 v = *reinterpret_cast<const us4*>(base + (size_t)c*NPOS);
      #pragma unroll
      for (int e = 0; e < 4; ++e){
        float f = bf2f(v[e]);
        s[e] += f; sq[e] += f*f;
      }
    }
    #pragma unroll
    for (int e = 0; e < 4; ++e){ part[grp][j4][e] = s[e]; part[grp][j4][4+e] = sq[e]; }
  }
  __syncthreads();
  if (t < 128){
    float s = 0.f, sq = 0.f;
    #pragma unroll
    for (int g2 = 0; g2 < 8; ++g2){
      s  += part[g2][t>>2][t&3];
      sq += part[g2][t>>2][4 + (t&3)];
    }
    float mu = s*(1.f/128.f);
    float var = sq*(1.f/128.f) - mu*mu;
    mu_s[t] = mu;
    rs_s[t] = rsqrtf(var + 1e-5f);
  }
  __syncthreads();

  { // phase B: L2-hot transposed re-read -> normalized bf16 pj[j][c]
    float mu = mu_s[r], rs = rs_s[r];
    const unsigned short* base = p_ws + (size_t)(h*64)*NPOS + (size_t)i*NSEQ + j0 + r;
    #pragma unroll
    for (int cc = 0; cc < 32; ++cc){
      int c0 = h*64 + 2*cc;
      float a = (bf2f(base[(size_t)(2*cc  )*NPOS]) - mu)*rs*ln2g[c0]   + ln2b[c0];
      float b = (bf2f(base[(size_t)(2*cc+1)*NPOS]) - mu)*rs*ln2g[c0+1] + ln2b[c0+1];
      *reinterpret_cast<unsigned int*>(&pj[r][c0]) =
          (unsigned int)f2bf(a) | ((unsigned int)f2bf(b) << 16);
    }
  }
  __syncthreads();

  const int lane = t & 63, wid = t >> 6;
  const int wrow = wid >> 1, wcol = wid & 1;
  const int lr_ = lane & 15, lq = lane >> 4;
  f32x4 acc[4][4];
  #pragma unroll
  for (int a1 = 0; a1 < 4; ++a1)
    #pragma unroll
    for (int a2 = 0; a2 < 4; ++a2) acc[a1][a2] = (f32x4){0.f,0.f,0.f,0.f};
  mfma_k128(pj, wop, wrow, wcol, lr_, lq, acc);

  // epilogue: out = Z_raw + g*(ab + bias); 16 lanes x fixed-j = 64B segments
  #pragma unroll
  for (int fi = 0; fi < 4; ++fi){
    #pragma unroll
    for (int e = 0; e < 4; ++e){
      int jr = j0 + wrow*64 + fi*16 + lq*4 + e;
      size_t rowoff = ((size_t)i*NSEQ + jr)*DDIM;
      #pragma unroll
      for (int fj = 0; fj < 4; ++fj){
        int dd = wcol*64 + fj*16 + lr_;
        size_t off = rowoff + dd;
        float ab = acc[fi][fj][e] + obias[dd];
        out[off] = Zraw[off] + bf2f(g_ws[off]) * ab;
      }
    }
  }
}

extern "C" void kernel_launch(void* const* d_in, const int* in_sizes, int n_in,
                              void* d_out, int out_size, void* d_ws, size_t ws_size,
                              hipStream_t stream) {
  const float* Zraw  = (const float*)d_in[0];
  const float* mask  = (const float*)d_in[1];
  const float* ln1g  = (const float*)d_in[2];
  const float* ln1b  = (const float*)d_in[3];
  const float* Wlr   = (const float*)d_in[4];
  const float* blr   = (const float*)d_in[5];
  const float* Wgate = (const float*)d_in[6];
  const float* bgate = (const float*)d_in[7];
  const float* Wog   = (const float*)d_in[8];
  const float* bog   = (const float*)d_in[9];
  const float* ln2g  = (const float*)d_in[10];
  const float* ln2b  = (const float*)d_in[11];
  const float* Wop   = (const float*)d_in[12];
  const float* obias = (const float*)d_in[13];
  float* out = (float*)d_out;

  // workspace layout (bf16 = ushort), total ~268.6 MB
  unsigned short* wt      = (unsigned short*)d_ws;          // 768*128
  unsigned short* left_t  = wt + 768*128;                   // [c][pos] 128*262144
  unsigned short* right_t = left_t + (size_t)DDIM*NPOS;
  unsigned short* g_ws    = right_t + (size_t)DDIM*NPOS;    // [pos][d]
  unsigned short* p_ws    = g_ws + (size_t)DDIM*NPOS;       // [c][i][j]

  k_prep<<<384, 256, 0, stream>>>(Wlr, Wgate, Wog, Wop, wt);
  k1<<<NPOS/128, 256, 0, stream>>>(Zraw, mask, ln1g, ln1b, blr, bgate, bog,
                                   wt, left_t, right_t, g_ws);
  k2<<<dim3(16, 128), 256, 0, stream>>>(left_t, right_t, p_ws);
  k3<<<NPOS/128, 256, 0, stream>>>(p_ws, g_ws, Zraw, ln2g, ln2b, wt, obias, out);
}